// Round 1
// baseline (361.723 us; speedup 1.0000x reference)
//
#include <hip/hip_runtime.h>

// S4 layer: B=8, L=4096, D=1024, N=128
// R3: LDS-free direct-fragment GEMMs (operands are 16B-contiguous in memory),
//     gemm2 keeps LDS only for the coalesced epilogue transpose (34 KB -> 4 blk/CU),
//     scan CHUNK 128->32 for 4x occupancy.
//   prep:  final_state (exact fp32) + Bw,Cw -> f16
//   gemm1: xp = x @ Bw^T   (512 blocks of 64x128, barrier-free streaming)
//   scan:  3-phase chunked parallel scan (fp32), CHUNK=32
//   gemm2: y = hs @ Cw^T + x*Dp  (2048 blocks of 128x128, K=128, direct frags)

typedef _Float16 half8 __attribute__((ext_vector_type(8)));
typedef _Float16 half4 __attribute__((ext_vector_type(4)));
typedef float f32x4 __attribute__((ext_vector_type(4)));

#define BDIM 8
#define LDIM 4096
#define DDIM 1024
#define NDIM 128
#define MTOT (BDIM * LDIM)       // 32768
#define CHUNK 32
#define NCHUNK (LDIM / CHUNK)    // 128
#define TOTCHUNK (BDIM * NCHUNK) // 1024

// ---------------- prep: final_state + convert Bw,Cw to f16 ----------------
__global__ __launch_bounds__(256) void prep(const float* __restrict__ x,
                                            const float* __restrict__ Bw,
                                            const float* __restrict__ Cw,
                                            _Float16* __restrict__ Bwh,
                                            _Float16* __restrict__ Cwh,
                                            float* __restrict__ out) {
    const int blk = blockIdx.x;
    const int t = threadIdx.x;
    if (blk < 128) {
        // final_state: out[b][n] = mean_b' dot(x[b',L-1,:], Bw[n,:])   (exact fp32)
        const int n = blk;
        float s = 0.f;
        const float* br = Bw + n * DDIM;
        for (int b = 0; b < BDIM; ++b) {
            const float* xr = x + ((size_t)b * LDIM + (LDIM - 1)) * DDIM;
            for (int k = t; k < DDIM; k += 256)
                s = fmaf(xr[k], br[k], s);
        }
        __shared__ float red[256];
        red[t] = s;
        __syncthreads();
        for (int off = 128; off > 0; off >>= 1) {
            if (t < off) red[t] += red[t + off];
            __syncthreads();
        }
        if (t == 0) {
            float v = red[0] * 0.125f;
            for (int b = 0; b < BDIM; ++b)
                out[(size_t)MTOT * DDIM + b * NDIM + n] = v;
        }
    } else {
        // convert 262144 fp32 (Bw 131072 then Cw 131072) to f16; 64 blocks x 4096 elems
        const int base = (blk - 128) * 4096;
#pragma unroll
        for (int j = 0; j < 4; ++j) {
            int e = base + j * 1024 + t * 4;
            const float* src;
            _Float16* dst;
            if (e < 131072) { src = Bw + e; dst = Bwh + e; }
            else            { src = Cw + (e - 131072); dst = Cwh + (e - 131072); }
            float4 v = *reinterpret_cast<const float4*>(src);
            half4 h = { (_Float16)v.x, (_Float16)v.y, (_Float16)v.z, (_Float16)v.w };
            *reinterpret_cast<half4*>(dst) = h;
        }
    }
}

// ---------------- GEMM1: xp[m][n] = sum_k x[m][k] * Bw[n][k] ----------------
// 64x128 tile, 4 waves (2x2: 32x64 each, 2x4 frags). Grid 512.
// No LDS, no barriers: A frag = 8 contiguous fp32 of an x row (convert in reg),
// B frag = 16B contiguous span of Bwh row (L2-resident, 256 KB total).
__global__ __launch_bounds__(256) void gemm1(const float* __restrict__ x,
                                             const _Float16* __restrict__ Bwh,
                                             float* __restrict__ xp) {
    const int t = threadIdx.x;
    const int row0 = blockIdx.x * 64;
    const int wave = t >> 6, lane = t & 63;
    const int wr = (wave >> 1) * 32, wc = (wave & 1) * 64;
    const int lrow = lane & 15, kq = (lane >> 4) * 8;

    f32x4 acc[2][4] = {};
    const float* a0 = x + (size_t)(row0 + wr + lrow) * DDIM + kq;
    const float* a1 = a0 + 16 * DDIM;
    const _Float16* b0 = Bwh + (size_t)(wc + lrow) * DDIM + kq;

    for (int kk = 0; kk < DDIM; kk += 32) {
        half8 bf[4];
#pragma unroll
        for (int ct = 0; ct < 4; ++ct)
            bf[ct] = *reinterpret_cast<const half8*>(b0 + (size_t)ct * 16 * DDIM + kk);
        half8 af[2];
#pragma unroll
        for (int rt = 0; rt < 2; ++rt) {
            const float* ap = (rt ? a1 : a0) + kk;
            float4 v0 = *reinterpret_cast<const float4*>(ap);
            float4 v1 = *reinterpret_cast<const float4*>(ap + 4);
            af[rt] = half8{ (_Float16)v0.x, (_Float16)v0.y, (_Float16)v0.z, (_Float16)v0.w,
                            (_Float16)v1.x, (_Float16)v1.y, (_Float16)v1.z, (_Float16)v1.w };
        }
#pragma unroll
        for (int rt = 0; rt < 2; ++rt)
#pragma unroll
            for (int ct = 0; ct < 4; ++ct)
                acc[rt][ct] = __builtin_amdgcn_mfma_f32_16x16x32_f16(af[rt], bf[ct], acc[rt][ct], 0, 0, 0);
    }

    const int q4 = (lane >> 4) * 4;
#pragma unroll
    for (int rt = 0; rt < 2; ++rt)
#pragma unroll
        for (int ct = 0; ct < 4; ++ct) {
            int col = wc + ct * 16 + lrow;
#pragma unroll
            for (int i = 0; i < 4; ++i)
                xp[(row0 + wr + rt * 16 + q4 + i) * NDIM + col] = acc[rt][ct][i];
        }
}

// ---------------- scan phase 1: per-chunk aggregates ----------------
__global__ void scan_agg(const float* __restrict__ xp, const float* __restrict__ logA,
                         float* __restrict__ agg) {
    const int chunk = blockIdx.x;
    const int n = threadIdx.x;
    const float A = expf(logA[n]);
    const float* u = xp + (size_t)chunk * CHUNK * NDIM + n;
    float h = 0.f;
#pragma unroll
    for (int j = 0; j < CHUNK; ++j)
        h = fmaf(A, h, u[j * NDIM]);
    agg[chunk * NDIM + n] = h;
}

// ---------------- scan phase 2: carries across chunks ----------------
__global__ void scan_carry(const float* __restrict__ agg, const float* __restrict__ logA,
                           float* __restrict__ hprev) {
    const int idx = blockIdx.x * blockDim.x + threadIdx.x;  // 1024
    const int b = idx >> 7, n = idx & 127;
    const float Ac = expf((float)CHUNK * logA[n]);
    float c = 0.f;
    for (int ch = 0; ch < NCHUNK; ++ch) {
        int g = (b * NCHUNK + ch) * NDIM + n;
        hprev[g] = c;
        c = fmaf(Ac, c, agg[g]);
    }
}

// ---------------- scan phase 3: final scan, write hs (f16) ----------------
__global__ void scan_final(const float* __restrict__ xp, const float* __restrict__ logA,
                           const float* __restrict__ hprev, _Float16* __restrict__ hs) {
    const int chunk = blockIdx.x;
    const int n = threadIdx.x;
    const float A = expf(logA[n]);
    float h = hprev[chunk * NDIM + n];
    const float* u = xp + (size_t)chunk * CHUNK * NDIM + n;
    _Float16* o = hs + (size_t)chunk * CHUNK * NDIM + n;
#pragma unroll
    for (int j = 0; j < CHUNK; ++j) {
        h = fmaf(A, h, u[j * NDIM]);
        o[j * NDIM] = (_Float16)h;
    }
}

// ---------------- GEMM2: y[m][d] = sum_n hs[m][n]*Cw[d][n] + x[m][d]*Dp[d] ----------------
// 128x128 tile, K=128 single shot. Direct fragment loads (hs L3-resident for
// the 8x column re-reads, Cwh L2-resident). LDS only for the coalesced
// float4 transpose epilogue (34 KB -> 4 blocks/CU).
#define BUFW 132
__global__ __launch_bounds__(256, 4) void gemm2(const _Float16* __restrict__ hs,
                                                const _Float16* __restrict__ Cwh,
                                                const float* __restrict__ x,
                                                const float* __restrict__ Dp,
                                                float* __restrict__ y) {
    __shared__ float buf[64 * BUFW];             // 33.8 KB epilogue transpose buffer
    __shared__ __align__(16) float DpS[128];

    const int t = threadIdx.x;
    const int row0 = blockIdx.x * 128;
    const int col0 = blockIdx.y * 128;
    const int wave = t >> 6, lane = t & 63;
    const int wr = (wave >> 1) * 64, wc = (wave & 1) * 64;
    const int lrow = lane & 15, kq = (lane >> 4) * 8;

    if (t < 128) DpS[t] = Dp[col0 + t];

    const _Float16* ha = hs + (size_t)(row0 + wr + lrow) * NDIM + kq;
    const _Float16* cb = Cwh + (size_t)(col0 + wc + lrow) * NDIM + kq;

    f32x4 acc[4][4] = {};
#pragma unroll
    for (int kb = 0; kb < 4; ++kb) {
        half8 bf[4], af[4];
#pragma unroll
        for (int ct = 0; ct < 4; ++ct)
            bf[ct] = *reinterpret_cast<const half8*>(cb + (size_t)ct * 16 * NDIM + kb * 32);
#pragma unroll
        for (int rt = 0; rt < 4; ++rt)
            af[rt] = *reinterpret_cast<const half8*>(ha + (size_t)rt * 16 * NDIM + kb * 32);
#pragma unroll
        for (int rt = 0; rt < 4; ++rt)
#pragma unroll
            for (int ct = 0; ct < 4; ++ct)
                acc[rt][ct] = __builtin_amdgcn_mfma_f32_16x16x32_f16(af[rt], bf[ct], acc[rt][ct], 0, 0, 0);
    }

    // epilogue: two 64-row halves through LDS fp32 buffer [64][BUFW]
    const int q4 = (lane >> 4) * 4;
#pragma unroll
    for (int half_ = 0; half_ < 2; ++half_) {
        __syncthreads();
        if ((wr >> 6) == half_) {
#pragma unroll
            for (int rt = 0; rt < 4; ++rt)
#pragma unroll
                for (int ct = 0; ct < 4; ++ct) {
                    int col = wc + ct * 16 + lrow;
#pragma unroll
                    for (int i = 0; i < 4; ++i)
                        buf[(rt * 16 + q4 + i) * BUFW + col] = acc[rt][ct][i];
                }
        }
        __syncthreads();
#pragma unroll
        for (int j = 0; j < 8; ++j) {
            int idx = t + 256 * j;
            int row = idx >> 5, c4 = idx & 31;
            int grow = row0 + half_ * 64 + row;
            float4 a = *reinterpret_cast<const float4*>(&buf[row * BUFW + c4 * 4]);
            float4 xv = *reinterpret_cast<const float4*>(&x[(size_t)grow * DDIM + col0 + c4 * 4]);
            float4 dp = *reinterpret_cast<const float4*>(&DpS[c4 * 4]);
            float4 o;
            o.x = a.x + xv.x * dp.x;
            o.y = a.y + xv.y * dp.y;
            o.z = a.z + xv.z * dp.z;
            o.w = a.w + xv.w * dp.w;
            *reinterpret_cast<float4*>(&y[(size_t)grow * DDIM + col0 + c4 * 4]) = o;
        }
    }
}

extern "C" void kernel_launch(void* const* d_in, const int* in_sizes, int n_in,
                              void* d_out, int out_size, void* d_ws, size_t ws_size,
                              hipStream_t stream) {
    const float* x    = (const float*)d_in[0];   // (8, 4096, 1024)
    const float* Bw   = (const float*)d_in[1];   // (128, 1024)
    const float* Cw   = (const float*)d_in[2];   // (1024, 128)
    const float* logA = (const float*)d_in[3];   // (128,)
    const float* Dp   = (const float*)d_in[4];   // (1024,)
    float* out = (float*)d_out;                  // y (33554432) + final_state (1024)

    char* ws = (char*)d_ws;
    float*    xp    = (float*)   (ws);                       // 16,777,216 B
    _Float16* hs    = (_Float16*)(ws + 16777216);            //  8,388,608 B
    float*    agg   = (float*)   (ws + 25165824);            //    524,288 B
    float*    hprev = (float*)   (ws + 25690112);            //    524,288 B
    _Float16* Bwh   = (_Float16*)(ws + 26214400);            //    262,144 B
    _Float16* Cwh   = (_Float16*)(ws + 26476544);            //    262,144 B

    prep<<<192, 256, 0, stream>>>(x, Bw, Cw, Bwh, Cwh, out);
    gemm1<<<MTOT / 64, 256, 0, stream>>>(x, Bwh, xp);
    scan_agg<<<TOTCHUNK, 128, 0, stream>>>(xp, logA, agg);
    scan_carry<<<4, 256, 0, stream>>>(agg, logA, hprev);
    scan_final<<<TOTCHUNK, 128, 0, stream>>>(xp, logA, hprev, hs);
    gemm2<<<dim3(MTOT / 128, DDIM / 128), 256, 0, stream>>>(hs, Cwh, x, Dp, out);
}